// Round 15
// baseline (293.369 us; speedup 1.0000x reference)
//
#include <hip/hip_runtime.h>
#include <hip/hip_fp16.h>
#include <hip/hip_cooperative_groups.h>

#define NN 100000
#define NE 625000
#define ND 128
#define NR 16
#define SLOPE 0.2f
#define NB 782             // src buckets: ceil(NN/128), 128 nodes each
#define CAP 1280           // slots/bucket; mean 799, +17 sigma
#define MAXE 5             // CAP/256 edges per thread in phase 2
#define NTILE 1563         // 64-node MFMA tiles (R11-proven granularity)
#define SC_EPB 4096        // edges per scatter block (16/thread) -- proven best
#define SC_BLOCKS 153      // ceil(NE/SC_EPB)
#define GRID 768           // 3 blocks/CU x 256 CUs, co-resident (cooperative)
#define LSTR 136           // LDS W row stride in bf16 elems (272 B, 16B-aligned)

using s16x8 = __attribute__((ext_vector_type(8))) short;
using f32x4 = __attribute__((ext_vector_type(4))) float;

// split float into bf16 hi (truncate) + bf16 lo (truncate of remainder)
__device__ __forceinline__ void bf_split(float x, unsigned short& h, unsigned short& l) {
    unsigned u = __float_as_uint(x);
    h = (unsigned short)(u >> 16);
    float hf = __uint_as_float(u & 0xFFFF0000u);
    l = (unsigned short)(__float_as_uint(x - hf) >> 16);
}

// One cooperative kernel, 3 phases separated by grid.sync():
//  P0: zero cursors/counters; ALL blocks stage W hi/lo in LDS (kept all kernel).
//  P1: blocks [0,153) scatter 4096 edges each into src-buckets (proven body);
//      then ALL blocks work-steal 64-node MFMA table tiles (self-balancing).
//  P2: all blocks work-steal fused softmax buckets (proven body, no global atomics).
__global__ __launch_bounds__(256, 3) void mega(
        const float* __restrict__ x, const float* __restrict__ a,
        const int* __restrict__ srcs, const int* __restrict__ dsts,
        const int* __restrict__ etype,
        __half* __restrict__ table, int2* __restrict__ bedge,
        unsigned* __restrict__ cursor,   // [NB] bucket cursors | [NB]=tileCtr | [NB+1]=bktCtr
        float* __restrict__ out) {
    cooperative_groups::grid_group grid = cooperative_groups::this_grid();
    __shared__ __align__(16) unsigned char smem[17408 + 3200];
    __shared__ unsigned shIdx;
    unsigned short* Wh = (unsigned short*)smem;           // 32 x LSTR
    unsigned short* Wl = Wh + 32 * LSTR;
    unsigned* hist = (unsigned*)(smem + 17408);           // [NB], role B only
    float* lsum = (float*)(smem + 17408);                 // [128], P2 (aliases hist)
    int tid = threadIdx.x;
    int b = blockIdx.x;

    // ---------------- phase 0 ----------------
    { int i = b * 256 + tid; if (i < NB + 2) cursor[i] = 0u; }
    // stage W: Wfull[o][k] = a[o&15][(o>>4)*128 + k], hi/lo split (every block)
#pragma unroll
    for (int i = 0; i < 4; ++i) {
        int f = tid + i * 256;                    // [0,1024) float4s
        int row = f >> 6;
        int c4 = f & 63;
        int o = row + ((c4 >> 5) << 4);
        int k = (c4 & 31) << 2;
        float4 v = *(const float4*)&a[(size_t)row * 256 + (size_t)c4 * 4];
        unsigned short h0, l0, h1, l1, h2, l2, h3, l3;
        bf_split(v.x, h0, l0); bf_split(v.y, h1, l1);
        bf_split(v.z, h2, l2); bf_split(v.w, h3, l3);
        *(uint2*)&Wh[o * LSTR + k] =
            make_uint2((unsigned)h0 | ((unsigned)h1 << 16),
                       (unsigned)h2 | ((unsigned)h3 << 16));
        *(uint2*)&Wl[o * LSTR + k] =
            make_uint2((unsigned)l0 | ((unsigned)l1 << 16),
                       (unsigned)l2 | ((unsigned)l3 << 16));
    }
    __syncthreads();
    grid.sync();

    // ---------------- phase 1 ----------------
    if (b < SC_BLOCKS) {
        // role B: bucket scatter (proven config)
        for (int j = tid; j < NB; j += 256) hist[j] = 0u;
        __syncthreads();
        int base = b * SC_EPB;
#pragma unroll
        for (int i = 0; i < 4; ++i) {
            int e = base + (i * 256 + tid) * 4;
            if (e < NE) {
                int4 s4 = *(const int4*)&srcs[e];
                atomicAdd(&hist[s4.x >> 7], 1u);
                atomicAdd(&hist[s4.y >> 7], 1u);
                atomicAdd(&hist[s4.z >> 7], 1u);
                atomicAdd(&hist[s4.w >> 7], 1u);
            }
        }
        __syncthreads();
        for (int j = tid; j < NB; j += 256) {
            unsigned c = hist[j];
            hist[j] = c ? atomicAdd(&cursor[j], c) : 0u;
        }
        __syncthreads();
#pragma unroll
        for (int i = 0; i < 4; ++i) {
            int e = base + (i * 256 + tid) * 4;
            if (e < NE) {
                int4 s4 = *(const int4*)&srcs[e];
                int4 d4 = *(const int4*)&dsts[e];
                int4 r4 = *(const int4*)&etype[e];
                int ss[4] = {s4.x, s4.y, s4.z, s4.w};
                int dd[4] = {d4.x, d4.y, d4.z, d4.w};
                int rr[4] = {r4.x, r4.y, r4.z, r4.w};
#pragma unroll
                for (int j = 0; j < 4; ++j) {
                    int bk = ss[j] >> 7;
                    unsigned slot = atomicAdd(&hist[bk], 1u);
                    if (slot < CAP) {
                        int w0 = (ss[j] & 127) | (rr[j] << 7) | (dd[j] << 11);
                        bedge[(size_t)bk * CAP + slot] = make_int2(w0, e + j);
                    }
                }
            }
        }
        __syncthreads();
    }
    // all blocks: work-steal 64-node MFMA tiles (R11-proven body)
    {
        int w = tid >> 6;
        int lane = tid & 63;
        int r16 = lane & 15;
        int q = lane >> 4;
        const unsigned short* w0h = &Wh[r16 * LSTR + q * 8];
        const unsigned short* w0l = &Wl[r16 * LSTR + q * 8];
        const unsigned short* w1h = &Wh[(16 + r16) * LSTR + q * 8];
        const unsigned short* w1l = &Wl[(16 + r16) * LSTR + q * 8];
        for (;;) {
            if (tid == 0) shIdx = atomicAdd(&cursor[NB], 1u);
            __syncthreads();
            unsigned t = shIdx;
            __syncthreads();
            if (t >= NTILE) break;
            int nb = (int)t * 64;
            int n = nb + w * 16 + r16;
            bool vld = n < NN;
            const float* xrow = x + (size_t)(vld ? n : 0) * ND + q * 8;
            f32x4 acc0 = {0.f, 0.f, 0.f, 0.f};
            f32x4 acc1 = {0.f, 0.f, 0.f, 0.f};
#pragma unroll
            for (int ks = 0; ks < 4; ++ks) {
                float4 v0 = vld ? *(const float4*)&xrow[ks * 32]
                                : make_float4(0.f, 0.f, 0.f, 0.f);
                float4 v1 = vld ? *(const float4*)&xrow[ks * 32 + 4]
                                : make_float4(0.f, 0.f, 0.f, 0.f);
                s16x8 ah, al;
                unsigned short h, lo;
                bf_split(v0.x, h, lo); ah[0]=(short)h; al[0]=(short)lo;
                bf_split(v0.y, h, lo); ah[1]=(short)h; al[1]=(short)lo;
                bf_split(v0.z, h, lo); ah[2]=(short)h; al[2]=(short)lo;
                bf_split(v0.w, h, lo); ah[3]=(short)h; al[3]=(short)lo;
                bf_split(v1.x, h, lo); ah[4]=(short)h; al[4]=(short)lo;
                bf_split(v1.y, h, lo); ah[5]=(short)h; al[5]=(short)lo;
                bf_split(v1.z, h, lo); ah[6]=(short)h; al[6]=(short)lo;
                bf_split(v1.w, h, lo); ah[7]=(short)h; al[7]=(short)lo;
                s16x8 bh0 = *(const s16x8*)&w0h[ks * 32];
                s16x8 bl0 = *(const s16x8*)&w0l[ks * 32];
                s16x8 bh1 = *(const s16x8*)&w1h[ks * 32];
                s16x8 bl1 = *(const s16x8*)&w1l[ks * 32];
                acc0 = __builtin_amdgcn_mfma_f32_16x16x32_bf16(ah, bh0, acc0, 0,0,0);
                acc0 = __builtin_amdgcn_mfma_f32_16x16x32_bf16(al, bh0, acc0, 0,0,0);
                acc0 = __builtin_amdgcn_mfma_f32_16x16x32_bf16(ah, bl0, acc0, 0,0,0);
                acc1 = __builtin_amdgcn_mfma_f32_16x16x32_bf16(ah, bh1, acc1, 0,0,0);
                acc1 = __builtin_amdgcn_mfma_f32_16x16x32_bf16(al, bh1, acc1, 0,0,0);
                acc1 = __builtin_amdgcn_mfma_f32_16x16x32_bf16(ah, bl1, acc1, 0,0,0);
            }
            int nrow = nb + w * 16 + q * 4;
#pragma unroll
            for (int r = 0; r < 4; ++r) {
                int nn = nrow + r;
                if (nn < NN) {
                    table[(size_t)nn * 32 + r16]      = __float2half_rn(acc0[r]);
                    table[(size_t)nn * 32 + 16 + r16] = __float2half_rn(acc1[r]);
                }
            }
        }
    }
    __threadfence();
    grid.sync();

    // ---------------- phase 2: work-steal fused softmax buckets ----------------
    for (;;) {
        if (tid == 0) shIdx = atomicAdd(&cursor[NB + 1], 1u);
        __syncthreads();
        unsigned bk = shIdx;
        __syncthreads();
        if (bk >= NB) break;
        if (tid < 128) lsum[tid] = 0.f;
        __syncthreads();

        unsigned count = cursor[bk];
        if (count > CAP) count = CAP;
        const int2* bin = bedge + (size_t)bk * CAP;

        int2 ed[MAXE];
        float u[MAXE], v[MAXE], ex[MAXE];
#pragma unroll
        for (int k = 0; k < MAXE; ++k) {
            unsigned i = tid + 256u * k;
            if (i < count) ed[k] = bin[i];
        }
#pragma unroll
        for (int k = 0; k < MAXE; ++k) {
            unsigned i = tid + 256u * k;
            if (i < count) {
                int w = ed[k].x;
                int sl = w & 127;
                int r  = (w >> 7) & 15;
                int d  = w >> 11;
                u[k] = __half2float(table[(size_t)((bk << 7) + sl) * 32 + r]);
                v[k] = __half2float(table[(size_t)d * 32 + 16 + r]);
            }
        }
#pragma unroll
        for (int k = 0; k < MAXE; ++k) {
            unsigned i = tid + 256u * k;
            if (i < count) {
                float av = u[k] + v[k];
                av = (av >= 0.f) ? av : SLOPE * av;
                ex[k] = __expf(av);
                atomicAdd(&lsum[ed[k].x & 127], ex[k]);   // ds_add_f32
            }
        }
        __syncthreads();
#pragma unroll
        for (int k = 0; k < MAXE; ++k) {
            unsigned i = tid + 256u * k;
            if (i < count)
                out[ed[k].y] = __fdividef(ex[k], lsum[ed[k].x & 127]);
        }
        __syncthreads();   // protect lsum before next iteration re-zeroes
    }
}

extern "C" void kernel_launch(void* const* d_in, const int* in_sizes, int n_in,
                              void* d_out, int out_size, void* d_ws, size_t ws_size,
                              hipStream_t stream) {
    const float* x     = (const float*)d_in[0];           // [NN, 128]
    const float* a     = (const float*)d_in[1];           // [16, 256]
    const int*   eidx  = (const int*)d_in[2];             // [2, NE]
    const int*   etype = (const int*)d_in[3];             // [NE]
    const int*   srcs  = eidx;
    const int*   dsts  = eidx + NE;
    float*       out   = (float*)d_out;

    // ws layout (8/16B-aligned)
    char* ws = (char*)d_ws;
    __half*   table  = (__half*)(ws);                      //  6,400,000 B
    int2*     bedge  = (int2*)(ws + 6400000);              //  8,007,680 B (NB*CAP*8)
    unsigned* cursor = (unsigned*)(ws + 14407680);         //  (NB+2)*4 B

    void* args[] = {(void*)&x, (void*)&a, (void*)&srcs, (void*)&dsts, (void*)&etype,
                    (void*)&table, (void*)&bedge, (void*)&cursor, (void*)&out};
    hipLaunchCooperativeKernel((const void*)mega, dim3(GRID), dim3(256),
                               args, 0, stream);
}

// Round 16
// 46.224 us; speedup vs baseline: 6.3467x; 6.3467x over previous
//
#include <hip/hip_runtime.h>
#include <hip/hip_fp16.h>

#define NN 100000
#define NE 625000
#define ND 128
#define NR 16
#define SLOPE 0.2f
#define NB 782             // src buckets: ceil(NN/128), 128 nodes each
#define CAP 1280           // slots/bucket; mean 799, +17 sigma
#define MAXE 5             // CAP/256 edges per thread in fused_abc
#define PRE_BLOCKS 1563    // ceil(NN/64): 64 nodes per MFMA block (proven best)
#define SC_EPB 4096        // edges per scatter block (16/thread) -- proven best
#define SC_BLOCKS 153      // ceil(NE/SC_EPB)
#define LSTR 136           // LDS W row stride in bf16 elems (128+8: 272 B, 16B-aligned)

using s16x8 = __attribute__((ext_vector_type(8))) short;
using f32x4 = __attribute__((ext_vector_type(4))) float;

// split float into bf16 hi (truncate) + bf16 lo (truncate of remainder):
// x ~= hi + lo with ~16 mantissa bits retained
__device__ __forceinline__ void bf_split(float x, unsigned short& h, unsigned short& l) {
    unsigned u = __float_as_uint(x);
    h = (unsigned short)(u >> 16);
    float hf = __uint_as_float(u & 0xFFFF0000u);
    l = (unsigned short)(__float_as_uint(x - hf) >> 16);
}

// Fused kernel, two roles by blockIdx (role B FIRST so it overlaps role A):
//  role B (blocks [0,153)): bin 4096 edges by (src>>7):
//    bedge[bk*CAP+slot] = {src_local|rel<<7|dst<<11, eid}; two-sweep LDS histogram
//    + one global cursor reservation per bucket per block.
//  role A (blocks [153,1716)): MFMA precompute of interleaved fp16 table:
//    table[n*32+o]: o<16: dot(a[o][0:128],x[n]); o>=16: dot(a[o-16][128:256],x[n]).
//    64 nodes/block. X,W split bf16 hi/lo; D = Xh*Wh + Xl*Wh + Xh*Wl (~fp32).
//    A-fragments loaded DIRECTLY global->reg (X rows are wave-private; lane l
//    needs x[row=l&15][k=(l>>4)*8+j] = two contiguous float4s per K-step).
//    Only W (shared) staged in LDS (17.4 KB).
__global__ __launch_bounds__(256) void pre_scatter(
        const float* __restrict__ x, const float* __restrict__ a,
        const int* __restrict__ srcs, const int* __restrict__ dsts,
        const int* __restrict__ etype,
        __half* __restrict__ table, int2* __restrict__ bedge,
        unsigned* __restrict__ cursor) {
    __shared__ __align__(16) unsigned short smem[2 * 32 * LSTR]; // Wh|Wl, 17,408 B
    int tid = threadIdx.x;
    int b = blockIdx.x;

    if (b >= SC_BLOCKS) {
        // ---------------- role A: MFMA precompute ----------------
        unsigned short* Wh = smem;                    // 32 x LSTR, rows = outputs o
        unsigned short* Wl = Wh + 32 * LSTR;
        int nb = (b - SC_BLOCKS) * 64;

        // stage W: Wfull[o][k] = a[o&15][(o>>4)*128 + k], 1024 float4s, hi/lo split
#pragma unroll
        for (int i = 0; i < 4; ++i) {
            int f = tid + i * 256;                    // [0,1024)
            int row = f >> 6;                         // a-row 0..15
            int c4 = f & 63;
            int o = row + ((c4 >> 5) << 4);
            int k = (c4 & 31) << 2;
            float4 v = *(const float4*)&a[(size_t)row * 256 + (size_t)c4 * 4];
            unsigned short h0, l0, h1, l1, h2, l2, h3, l3;
            bf_split(v.x, h0, l0); bf_split(v.y, h1, l1);
            bf_split(v.z, h2, l2); bf_split(v.w, h3, l3);
            *(uint2*)&Wh[o * LSTR + k] =
                make_uint2((unsigned)h0 | ((unsigned)h1 << 16),
                           (unsigned)h2 | ((unsigned)h3 << 16));
            *(uint2*)&Wl[o * LSTR + k] =
                make_uint2((unsigned)l0 | ((unsigned)l1 << 16),
                           (unsigned)l2 | ((unsigned)l3 << 16));
        }
        __syncthreads();

        int w = tid >> 6;          // wave id = M-tile
        int lane = tid & 63;
        int r16 = lane & 15;       // A row within tile / B col within tile
        int q = lane >> 4;         // k-octet selector

        int n = nb + w * 16 + r16;
        bool vld = n < NN;
        const float* xrow = x + (size_t)(vld ? n : 0) * ND + q * 8;

        f32x4 acc0 = {0.f, 0.f, 0.f, 0.f};
        f32x4 acc1 = {0.f, 0.f, 0.f, 0.f};
        const unsigned short* w0h = &Wh[r16 * LSTR + q * 8];          // N-tile 0
        const unsigned short* w0l = &Wl[r16 * LSTR + q * 8];
        const unsigned short* w1h = &Wh[(16 + r16) * LSTR + q * 8];   // N-tile 1
        const unsigned short* w1l = &Wl[(16 + r16) * LSTR + q * 8];
#pragma unroll
        for (int ks = 0; ks < 4; ++ks) {
            float4 v0 = vld ? *(const float4*)&xrow[ks * 32]
                            : make_float4(0.f, 0.f, 0.f, 0.f);
            float4 v1 = vld ? *(const float4*)&xrow[ks * 32 + 4]
                            : make_float4(0.f, 0.f, 0.f, 0.f);
            s16x8 ah, al;
            unsigned short h, lo;
            bf_split(v0.x, h, lo); ah[0] = (short)h; al[0] = (short)lo;
            bf_split(v0.y, h, lo); ah[1] = (short)h; al[1] = (short)lo;
            bf_split(v0.z, h, lo); ah[2] = (short)h; al[2] = (short)lo;
            bf_split(v0.w, h, lo); ah[3] = (short)h; al[3] = (short)lo;
            bf_split(v1.x, h, lo); ah[4] = (short)h; al[4] = (short)lo;
            bf_split(v1.y, h, lo); ah[5] = (short)h; al[5] = (short)lo;
            bf_split(v1.z, h, lo); ah[6] = (short)h; al[6] = (short)lo;
            bf_split(v1.w, h, lo); ah[7] = (short)h; al[7] = (short)lo;

            s16x8 bh0 = *(const s16x8*)&w0h[ks * 32];
            s16x8 bl0 = *(const s16x8*)&w0l[ks * 32];
            s16x8 bh1 = *(const s16x8*)&w1h[ks * 32];
            s16x8 bl1 = *(const s16x8*)&w1l[ks * 32];
            acc0 = __builtin_amdgcn_mfma_f32_16x16x32_bf16(ah, bh0, acc0, 0, 0, 0);
            acc0 = __builtin_amdgcn_mfma_f32_16x16x32_bf16(al, bh0, acc0, 0, 0, 0);
            acc0 = __builtin_amdgcn_mfma_f32_16x16x32_bf16(ah, bl0, acc0, 0, 0, 0);
            acc1 = __builtin_amdgcn_mfma_f32_16x16x32_bf16(ah, bh1, acc1, 0, 0, 0);
            acc1 = __builtin_amdgcn_mfma_f32_16x16x32_bf16(al, bh1, acc1, 0, 0, 0);
            acc1 = __builtin_amdgcn_mfma_f32_16x16x32_bf16(ah, bl1, acc1, 0, 0, 0);
        }
        // D layout: col = lane&15, row = (lane>>4)*4 + reg
        int nrow = nb + w * 16 + q * 4;
#pragma unroll
        for (int r = 0; r < 4; ++r) {
            int nn = nrow + r;
            if (nn < NN) {
                table[(size_t)nn * 32 + r16]      = __float2half_rn(acc0[r]);
                table[(size_t)nn * 32 + 16 + r16] = __float2half_rn(acc1[r]);
            }
        }
    } else {
        // ---------------- role B: bucket scatter (proven config) ----------------
        unsigned* hist = (unsigned*)smem;      // [NB] = 3,128 B (aliases W area)
        for (int j = tid; j < NB; j += 256) hist[j] = 0u;
        __syncthreads();

        int base = b * SC_EPB;
        // sweep 1: per-bucket counts
#pragma unroll
        for (int i = 0; i < 4; ++i) {
            int e = base + (i * 256 + tid) * 4;
            if (e < NE) {                      // NE % 4 == 0: whole int4 valid
                int4 s4 = *(const int4*)&srcs[e];
                atomicAdd(&hist[s4.x >> 7], 1u);
                atomicAdd(&hist[s4.y >> 7], 1u);
                atomicAdd(&hist[s4.z >> 7], 1u);
                atomicAdd(&hist[s4.w >> 7], 1u);
            }
        }
        __syncthreads();
        // reserve global ranges; hist[j] becomes this block's running cursor
        for (int j = tid; j < NB; j += 256) {
            unsigned c = hist[j];
            hist[j] = c ? atomicAdd(&cursor[j], c) : 0u;
        }
        __syncthreads();
        // sweep 2: place edges
#pragma unroll
        for (int i = 0; i < 4; ++i) {
            int e = base + (i * 256 + tid) * 4;
            if (e < NE) {
                int4 s4 = *(const int4*)&srcs[e];
                int4 d4 = *(const int4*)&dsts[e];
                int4 r4 = *(const int4*)&etype[e];
                int ss[4] = {s4.x, s4.y, s4.z, s4.w};
                int dd[4] = {d4.x, d4.y, d4.z, d4.w};
                int rr[4] = {r4.x, r4.y, r4.z, r4.w};
#pragma unroll
                for (int j = 0; j < 4; ++j) {
                    int bk = ss[j] >> 7;
                    unsigned slot = atomicAdd(&hist[bk], 1u);
                    if (slot < CAP) {
                        int w0 = (ss[j] & 127) | (rr[j] << 7) | (dd[j] << 11);
                        bedge[(size_t)bk * CAP + slot] = make_int2(w0, e + j);
                    }
                }
            }
        }
    }
}

// One block per src-bucket: every edge with src in [b*128,(b+1)*128) is here.
// Phase 1: gather u (8 KB-local slab) + v (random), ex = exp(lrelu(u+v))
//          (softmax shift-invariant, |e|<~12 -> no max pass),
//          segment-sum in LDS (ds_add_f32) -- NO global atomics anywhere.
// Phase 2: out[eid] = ex / lsum[src_local].
__global__ __launch_bounds__(256) void fused_abc(
        const unsigned* __restrict__ cursor, const int2* __restrict__ bedge,
        const __half* __restrict__ table, float* __restrict__ out) {
    __shared__ float lsum[128];
    int b = blockIdx.x;
    int tid = threadIdx.x;
    if (tid < 128) lsum[tid] = 0.f;
    __syncthreads();

    unsigned count = cursor[b];
    if (count > CAP) count = CAP;
    const int2* bin = bedge + (size_t)b * CAP;

    int2 ed[MAXE];
    float u[MAXE], v[MAXE], ex[MAXE];

#pragma unroll
    for (int k = 0; k < MAXE; ++k) {
        unsigned i = tid + 256u * k;
        if (i < count) ed[k] = bin[i];
    }
#pragma unroll
    for (int k = 0; k < MAXE; ++k) {
        unsigned i = tid + 256u * k;
        if (i < count) {
            int w = ed[k].x;
            int sl = w & 127;
            int r  = (w >> 7) & 15;
            int d  = w >> 11;
            u[k] = __half2float(table[(size_t)((b << 7) + sl) * 32 + r]);
            v[k] = __half2float(table[(size_t)d * 32 + 16 + r]);
        }
    }
#pragma unroll
    for (int k = 0; k < MAXE; ++k) {
        unsigned i = tid + 256u * k;
        if (i < count) {
            float av = u[k] + v[k];
            av = (av >= 0.f) ? av : SLOPE * av;
            ex[k] = __expf(av);
            atomicAdd(&lsum[ed[k].x & 127], ex[k]);   // ds_add_f32
        }
    }
    __syncthreads();
#pragma unroll
    for (int k = 0; k < MAXE; ++k) {
        unsigned i = tid + 256u * k;
        if (i < count)
            out[ed[k].y] = __fdividef(ex[k], lsum[ed[k].x & 127]);
    }
}

extern "C" void kernel_launch(void* const* d_in, const int* in_sizes, int n_in,
                              void* d_out, int out_size, void* d_ws, size_t ws_size,
                              hipStream_t stream) {
    const float* x     = (const float*)d_in[0];           // [NN, 128]
    const float* a     = (const float*)d_in[1];           // [16, 256]
    const int*   eidx  = (const int*)d_in[2];             // [2, NE]
    const int*   etype = (const int*)d_in[3];             // [NE]
    const int*   srcs  = eidx;
    const int*   dsts  = eidx + NE;
    float*       out   = (float*)d_out;

    // ws layout (8/16B-aligned)
    char* ws = (char*)d_ws;
    __half*   table  = (__half*)(ws);                      //  6,400,000 B
    int2*     bedge  = (int2*)(ws + 6400000);              //  8,007,680 B (NB*CAP*8)
    unsigned* cursor = (unsigned*)(ws + 14407680);         //      3,128 B

    dim3 blk(256);
    hipMemsetAsync(cursor, 0, NB * sizeof(unsigned), stream);   // graph memset node
    pre_scatter<<<dim3(PRE_BLOCKS + SC_BLOCKS), blk, 0, stream>>>(
        x, a, srcs, dsts, etype, table, bedge, cursor);
    fused_abc<<<dim3(NB), blk, 0, stream>>>(cursor, bedge, table, out);
}

// Round 17
// 44.448 us; speedup vs baseline: 6.6003x; 1.0399x over previous
//
#include <hip/hip_runtime.h>
#include <hip/hip_fp16.h>

#define NN 100000
#define NE 625000
#define ND 128
#define NR 16
#define SLOPE 0.2f
#define NB 782             // src buckets: ceil(NN/128), 128 nodes each
#define CAP 1280           // slots/bucket; mean 799, +17 sigma
#define MAXE 5             // CAP/256 edges per thread in fused_abc
#define PRE_BLOCKS 1563    // ceil(NN/64): 64 nodes per MFMA block (proven best)
#define SC_EPB 4096        // edges per scatter block (16/thread) -- proven best
#define SC_BLOCKS 153      // ceil(NE/SC_EPB)
#define LSTR 136           // LDS W row stride in bf16 elems (128+8: 272 B, 16B-aligned)

using s16x8 = __attribute__((ext_vector_type(8))) short;
using f32x4 = __attribute__((ext_vector_type(4))) float;

__global__ void zero_cursor(unsigned* __restrict__ c) {
    int i = blockIdx.x * 256 + threadIdx.x;
    if (i < NB) c[i] = 0u;
}

// split float into bf16 hi (truncate) + bf16 lo (truncate of remainder):
// x ~= hi + lo with ~16 mantissa bits retained
__device__ __forceinline__ void bf_split(float x, unsigned short& h, unsigned short& l) {
    unsigned u = __float_as_uint(x);
    h = (unsigned short)(u >> 16);
    float hf = __uint_as_float(u & 0xFFFF0000u);
    l = (unsigned short)(__float_as_uint(x - hf) >> 16);
}

// Fused kernel, two roles by blockIdx (role B FIRST so it overlaps role A):
//  role B (blocks [0,153)): bin 4096 edges by (src>>7):
//    bedge[bk*CAP+slot] = {src_local|rel<<7|dst<<11, eid}; two-sweep LDS histogram
//    + one global cursor reservation per bucket per block.
//  role A (blocks [153,1716)): MFMA precompute of interleaved fp16 table:
//    table[n*32+o]: o<16: dot(a[o][0:128],x[n]); o>=16: dot(a[o-16][128:256],x[n]).
//    64 nodes/block. X,W split bf16 hi/lo; D = Xh*Wh + Xl*Wh + Xh*Wl (~fp32).
//    A-fragments loaded DIRECTLY global->reg (X rows are wave-private; lane l
//    needs x[row=l&15][k=(l>>4)*8+j] = two contiguous float4s per K-step).
//    Only W (shared) staged in LDS (17.4 KB).
__global__ __launch_bounds__(256) void pre_scatter(
        const float* __restrict__ x, const float* __restrict__ a,
        const int* __restrict__ srcs, const int* __restrict__ dsts,
        const int* __restrict__ etype,
        __half* __restrict__ table, int2* __restrict__ bedge,
        unsigned* __restrict__ cursor) {
    __shared__ __align__(16) unsigned short smem[2 * 32 * LSTR]; // Wh|Wl, 17,408 B
    int tid = threadIdx.x;
    int b = blockIdx.x;

    if (b >= SC_BLOCKS) {
        // ---------------- role A: MFMA precompute ----------------
        unsigned short* Wh = smem;                    // 32 x LSTR, rows = outputs o
        unsigned short* Wl = Wh + 32 * LSTR;
        int nb = (b - SC_BLOCKS) * 64;

        // stage W: Wfull[o][k] = a[o&15][(o>>4)*128 + k], 1024 float4s, hi/lo split
#pragma unroll
        for (int i = 0; i < 4; ++i) {
            int f = tid + i * 256;                    // [0,1024)
            int row = f >> 6;                         // a-row 0..15
            int c4 = f & 63;
            int o = row + ((c4 >> 5) << 4);
            int k = (c4 & 31) << 2;
            float4 v = *(const float4*)&a[(size_t)row * 256 + (size_t)c4 * 4];
            unsigned short h0, l0, h1, l1, h2, l2, h3, l3;
            bf_split(v.x, h0, l0); bf_split(v.y, h1, l1);
            bf_split(v.z, h2, l2); bf_split(v.w, h3, l3);
            *(uint2*)&Wh[o * LSTR + k] =
                make_uint2((unsigned)h0 | ((unsigned)h1 << 16),
                           (unsigned)h2 | ((unsigned)h3 << 16));
            *(uint2*)&Wl[o * LSTR + k] =
                make_uint2((unsigned)l0 | ((unsigned)l1 << 16),
                           (unsigned)l2 | ((unsigned)l3 << 16));
        }
        __syncthreads();

        int w = tid >> 6;          // wave id = M-tile
        int lane = tid & 63;
        int r16 = lane & 15;       // A row within tile / B col within tile
        int q = lane >> 4;         // k-octet selector

        int n = nb + w * 16 + r16;
        bool vld = n < NN;
        const float* xrow = x + (size_t)(vld ? n : 0) * ND + q * 8;

        f32x4 acc0 = {0.f, 0.f, 0.f, 0.f};
        f32x4 acc1 = {0.f, 0.f, 0.f, 0.f};
        const unsigned short* w0h = &Wh[r16 * LSTR + q * 8];          // N-tile 0
        const unsigned short* w0l = &Wl[r16 * LSTR + q * 8];
        const unsigned short* w1h = &Wh[(16 + r16) * LSTR + q * 8];   // N-tile 1
        const unsigned short* w1l = &Wl[(16 + r16) * LSTR + q * 8];
#pragma unroll
        for (int ks = 0; ks < 4; ++ks) {
            float4 v0 = vld ? *(const float4*)&xrow[ks * 32]
                            : make_float4(0.f, 0.f, 0.f, 0.f);
            float4 v1 = vld ? *(const float4*)&xrow[ks * 32 + 4]
                            : make_float4(0.f, 0.f, 0.f, 0.f);
            s16x8 ah, al;
            unsigned short h, lo;
            bf_split(v0.x, h, lo); ah[0] = (short)h; al[0] = (short)lo;
            bf_split(v0.y, h, lo); ah[1] = (short)h; al[1] = (short)lo;
            bf_split(v0.z, h, lo); ah[2] = (short)h; al[2] = (short)lo;
            bf_split(v0.w, h, lo); ah[3] = (short)h; al[3] = (short)lo;
            bf_split(v1.x, h, lo); ah[4] = (short)h; al[4] = (short)lo;
            bf_split(v1.y, h, lo); ah[5] = (short)h; al[5] = (short)lo;
            bf_split(v1.z, h, lo); ah[6] = (short)h; al[6] = (short)lo;
            bf_split(v1.w, h, lo); ah[7] = (short)h; al[7] = (short)lo;

            s16x8 bh0 = *(const s16x8*)&w0h[ks * 32];
            s16x8 bl0 = *(const s16x8*)&w0l[ks * 32];
            s16x8 bh1 = *(const s16x8*)&w1h[ks * 32];
            s16x8 bl1 = *(const s16x8*)&w1l[ks * 32];
            acc0 = __builtin_amdgcn_mfma_f32_16x16x32_bf16(ah, bh0, acc0, 0, 0, 0);
            acc0 = __builtin_amdgcn_mfma_f32_16x16x32_bf16(al, bh0, acc0, 0, 0, 0);
            acc0 = __builtin_amdgcn_mfma_f32_16x16x32_bf16(ah, bl0, acc0, 0, 0, 0);
            acc1 = __builtin_amdgcn_mfma_f32_16x16x32_bf16(ah, bh1, acc1, 0, 0, 0);
            acc1 = __builtin_amdgcn_mfma_f32_16x16x32_bf16(al, bh1, acc1, 0, 0, 0);
            acc1 = __builtin_amdgcn_mfma_f32_16x16x32_bf16(ah, bl1, acc1, 0, 0, 0);
        }
        // D layout: col = lane&15, row = (lane>>4)*4 + reg
        int nrow = nb + w * 16 + q * 4;
#pragma unroll
        for (int r = 0; r < 4; ++r) {
            int nn = nrow + r;
            if (nn < NN) {
                table[(size_t)nn * 32 + r16]      = __float2half_rn(acc0[r]);
                table[(size_t)nn * 32 + 16 + r16] = __float2half_rn(acc1[r]);
            }
        }
    } else {
        // ---------------- role B: bucket scatter (proven config) ----------------
        unsigned* hist = (unsigned*)smem;      // [NB] = 3,128 B (aliases W area)
        for (int j = tid; j < NB; j += 256) hist[j] = 0u;
        __syncthreads();

        int base = b * SC_EPB;
        // sweep 1: per-bucket counts
#pragma unroll
        for (int i = 0; i < 4; ++i) {
            int e = base + (i * 256 + tid) * 4;
            if (e < NE) {                      // NE % 4 == 0: whole int4 valid
                int4 s4 = *(const int4*)&srcs[e];
                atomicAdd(&hist[s4.x >> 7], 1u);
                atomicAdd(&hist[s4.y >> 7], 1u);
                atomicAdd(&hist[s4.z >> 7], 1u);
                atomicAdd(&hist[s4.w >> 7], 1u);
            }
        }
        __syncthreads();
        // reserve global ranges; hist[j] becomes this block's running cursor
        for (int j = tid; j < NB; j += 256) {
            unsigned c = hist[j];
            hist[j] = c ? atomicAdd(&cursor[j], c) : 0u;
        }
        __syncthreads();
        // sweep 2: place edges
#pragma unroll
        for (int i = 0; i < 4; ++i) {
            int e = base + (i * 256 + tid) * 4;
            if (e < NE) {
                int4 s4 = *(const int4*)&srcs[e];
                int4 d4 = *(const int4*)&dsts[e];
                int4 r4 = *(const int4*)&etype[e];
                int ss[4] = {s4.x, s4.y, s4.z, s4.w};
                int dd[4] = {d4.x, d4.y, d4.z, d4.w};
                int rr[4] = {r4.x, r4.y, r4.z, r4.w};
#pragma unroll
                for (int j = 0; j < 4; ++j) {
                    int bk = ss[j] >> 7;
                    unsigned slot = atomicAdd(&hist[bk], 1u);
                    if (slot < CAP) {
                        int w0 = (ss[j] & 127) | (rr[j] << 7) | (dd[j] << 11);
                        bedge[(size_t)bk * CAP + slot] = make_int2(w0, e + j);
                    }
                }
            }
        }
    }
}

// One block per src-bucket: every edge with src in [b*128,(b+1)*128) is here.
// Phase 1: gather u (8 KB-local slab) + v (random), ex = exp(lrelu(u+v))
//          (softmax shift-invariant, |e|<~12 -> no max pass),
//          segment-sum in LDS (ds_add_f32) -- NO global atomics anywhere.
// Phase 2: out[eid] = ex / lsum[src_local].
__global__ __launch_bounds__(256) void fused_abc(
        const unsigned* __restrict__ cursor, const int2* __restrict__ bedge,
        const __half* __restrict__ table, float* __restrict__ out) {
    __shared__ float lsum[128];
    int b = blockIdx.x;
    int tid = threadIdx.x;
    if (tid < 128) lsum[tid] = 0.f;
    __syncthreads();

    unsigned count = cursor[b];
    if (count > CAP) count = CAP;
    const int2* bin = bedge + (size_t)b * CAP;

    int2 ed[MAXE];
    float u[MAXE], v[MAXE], ex[MAXE];

#pragma unroll
    for (int k = 0; k < MAXE; ++k) {
        unsigned i = tid + 256u * k;
        if (i < count) ed[k] = bin[i];
    }
#pragma unroll
    for (int k = 0; k < MAXE; ++k) {
        unsigned i = tid + 256u * k;
        if (i < count) {
            int w = ed[k].x;
            int sl = w & 127;
            int r  = (w >> 7) & 15;
            int d  = w >> 11;
            u[k] = __half2float(table[(size_t)((b << 7) + sl) * 32 + r]);
            v[k] = __half2float(table[(size_t)d * 32 + 16 + r]);
        }
    }
#pragma unroll
    for (int k = 0; k < MAXE; ++k) {
        unsigned i = tid + 256u * k;
        if (i < count) {
            float av = u[k] + v[k];
            av = (av >= 0.f) ? av : SLOPE * av;
            ex[k] = __expf(av);
            atomicAdd(&lsum[ed[k].x & 127], ex[k]);   // ds_add_f32
        }
    }
    __syncthreads();
#pragma unroll
    for (int k = 0; k < MAXE; ++k) {
        unsigned i = tid + 256u * k;
        if (i < count)
            out[ed[k].y] = __fdividef(ex[k], lsum[ed[k].x & 127]);
    }
}

extern "C" void kernel_launch(void* const* d_in, const int* in_sizes, int n_in,
                              void* d_out, int out_size, void* d_ws, size_t ws_size,
                              hipStream_t stream) {
    const float* x     = (const float*)d_in[0];           // [NN, 128]
    const float* a     = (const float*)d_in[1];           // [16, 256]
    const int*   eidx  = (const int*)d_in[2];             // [2, NE]
    const int*   etype = (const int*)d_in[3];             // [NE]
    const int*   srcs  = eidx;
    const int*   dsts  = eidx + NE;
    float*       out   = (float*)d_out;

    // ws layout (8/16B-aligned)
    char* ws = (char*)d_ws;
    __half*   table  = (__half*)(ws);                      //  6,400,000 B
    int2*     bedge  = (int2*)(ws + 6400000);              //  8,007,680 B (NB*CAP*8)
    unsigned* cursor = (unsigned*)(ws + 14407680);         //      3,128 B

    dim3 blk(256);
    zero_cursor<<<dim3(4), blk, 0, stream>>>(cursor);
    pre_scatter<<<dim3(PRE_BLOCKS + SC_BLOCKS), blk, 0, stream>>>(
        x, a, srcs, dsts, etype, table, bedge, cursor);
    fused_abc<<<dim3(NB), blk, 0, stream>>>(cursor, bedge, table, out);
}